// Round 29
// baseline (278.937 us; speedup 1.0000x reference)
//
#include <hip/hip_runtime.h>

// RWKV6Attention forward — round 29: R28 base (262.3us) + xmw f16 (the last
// f32 intermediate): kA2m5's largest write halves (16.8->8.4MB) and kWL's
// read halves. kA2m5 epilogue now branch-free (all 5 planes emit f16).
// Error budget ~1-3e-3 via w-path exp-cumsum analysis; margin >=1.7x.

#define DEVI __device__ __forceinline__

namespace {

typedef unsigned short u16;
typedef unsigned int u32;
typedef __attribute__((ext_vector_type(8))) _Float16 f16x8;  // 4 VGPRs
typedef __attribute__((ext_vector_type(4))) float f32x4;

typedef __attribute__((address_space(1))) const u32 gu32;
typedef __attribute__((address_space(3))) u32 lu32;

constexpr int Lc = 2048;
constexpr int Tc = 4096;   // B*L

// ---- workspace layout (byte offsets), lifetime-safe aliasing.
constexpr size_t OFF_WKV    = 0;           // f16 [512][128][256] (kD1+)
constexpr size_t OFF_XM0F   = 0;           //   f16 [T][1024] (kWA -> kA2f/kA2m5, dead before kD1)
constexpr size_t OFF_DELTAF = 16777216;    //   f16 [T][1024] (kWA -> kA2m5, dead before kD1)
constexpr size_t OFF_T160   = 33554432;    // f32 [T][160]  dead after kA2m5
constexpr size_t OFF_XMW    = 36175872;    // f16 [T][1024] (kA2m5 -> kWL)
constexpr size_t OFF_X0WF   = 54001664;    // f16 [160][1024]
constexpr size_t OFF_YWP    = 56623104;    // f32 [4][T][64] (kWL -> kC)
constexpr size_t OFF_XMF    = 67108864;    // f16 [4][T][1024] (kA2m5 -> kB)
constexpr size_t OFF_WFIN   = 67108864;    //   f32 [T][512]  (kC -> kD1, after kB)
constexpr size_t OFF_GATE   = 75497472;    //   f16 [T][1024] (kD3 -> kF)
constexpr size_t OFF_QE     = 100663296;   // f16 [T][512] (kD1 -> kD3)
constexpr size_t OFF_OO     = 109051904;   // f16 [T][1024] o_intra (kD1 -> kD3)
constexpr size_t OFF_WF     = 125829120;   // f16 [3072][1024]
constexpr size_t OFF_DECAY  = 132120576;
constexpr size_t OFF_OWB    = 136314880;   // f16 [1024][1024]
constexpr size_t OFF_RG     = 138412032;   // f16 [T][512]
constexpr size_t OFF_KG     = 146800640;   // f16 [T][512]
constexpr size_t OFF_VG     = 155189248;   // f16 [T][1024]
constexpr size_t OFF_GG     = 171966464;   // f16 [T][1024]
constexpr size_t WS_NEED    = 180355072;

DEVI float4 ld4(const float* p) { return *reinterpret_cast<const float4*>(p); }
DEVI void   st4(float* p, float4 v) { *reinterpret_cast<float4*>(p) = v; }
DEVI u16 f2h(float f) { _Float16 h = (_Float16)f; return *(u16*)&h; }
DEVI float h2f(u16 u) { _Float16 h = *(_Float16*)&u; return (float)h; }

// ---- BK=64 swizzled staging (source-side XOR; linear LDS dest)
DEVI void stage_swz(const u16* __restrict__ src, u16* __restrict__ dstBase,
                    int srow8, int k0, int lane) {
  const int rr = srow8 + (lane >> 3);
  const int ss = (lane & 7) ^ ((lane >> 3) & 7);
  __builtin_amdgcn_global_load_lds(
      (gu32*)(const void*)(src + (size_t)rr * 1024 + k0 + ss * 8),
      (lu32*)(void*)(dstBase + srow8 * 64), 16, 0, 0);
}
DEVI f16x8 read_swz(const u16* __restrict__ buf, int row, int slot_lin) {
  return *reinterpret_cast<const f16x8*>(buf + row * 64 + ((slot_lin ^ (row & 7)) * 8));
}

// ---------------------------------------------------------------- kernel WA
__global__ void kWA(const float* __restrict__ r_w, const float* __restrict__ k_w,
                    const float* __restrict__ v_w, const float* __restrict__ g_w,
                    const float* __restrict__ o_w, const float* __restrict__ x0_w,
                    const float* __restrict__ x, const float* __restrict__ x0_mu,
                    u16* __restrict__ Wf, u16* __restrict__ owb,
                    u16* __restrict__ x0wf, u16* __restrict__ xm0f,
                    u16* __restrict__ deltaf) {
  if (blockIdx.x < 4256) {
    const size_t i = ((size_t)blockIdx.x * 256 + threadIdx.x) * 4;
    const float* src;
    u16* dst;
    if (i < 3145728) {
      src = (i < 524288)  ? r_w + i
          : (i < 1048576) ? k_w + (i - 524288)
          : (i < 2097152) ? v_w + (i - 1048576)
                          : g_w + (i - 2097152);
      dst = Wf + i;
    } else if (i < 4194304) {
      src = o_w + (i - 3145728);
      dst = owb + (i - 3145728);
    } else {
      src = x0_w + (i - 4194304);
      dst = x0wf + (i - 4194304);
    }
    float4 v = ld4(src);
    ushort4 h;
    h.x = f2h(v.x); h.y = f2h(v.y); h.z = f2h(v.z); h.w = f2h(v.w);
    *reinterpret_cast<ushort4*>(dst) = h;
  } else {
    const size_t i4 = (size_t)(blockIdx.x - 4256) * 256 + threadIdx.x;
    const int t = (int)(i4 >> 8);
    const int h4 = (int)(i4 & 255) * 4;
    float4 xv = ld4(x + (size_t)t * 1024 + h4);
    float4 xp = make_float4(0.f, 0.f, 0.f, 0.f);
    if (t & (Lc - 1)) xp = ld4(x + (size_t)(t - 1) * 1024 + h4);
    float4 mu = ld4(x0_mu + h4);
    float4 d;
    d.x = xp.x - xv.x; d.y = xp.y - xv.y; d.z = xp.z - xv.z; d.w = xp.w - xv.w;
    ushort4 dh;
    dh.x = f2h(d.x); dh.y = f2h(d.y); dh.z = f2h(d.z); dh.w = f2h(d.w);
    *reinterpret_cast<ushort4*>(deltaf + (size_t)t * 1024 + h4) = dh;
    float4 m0;
    m0.x = xv.x + d.x * mu.x; m0.y = xv.y + d.y * mu.y;
    m0.z = xv.z + d.z * mu.z; m0.w = xv.w + d.w * mu.w;
    ushort4 h;
    h.x = f2h(m0.x); h.y = f2h(m0.y); h.z = f2h(m0.z); h.w = f2h(m0.w);
    *reinterpret_cast<ushort4*>(xm0f + (size_t)t * 1024 + h4) = h;
  }
}

// ---------------------------------------------------------------- kernel A2f
__global__ __launch_bounds__(256) void kA2f(
    const u16* __restrict__ xm0f, const u16* __restrict__ x0wf,
    float* __restrict__ t160) {
  __shared__ __align__(16) u16 sA[128 * 64];
  __shared__ __align__(16) u16 sB[128 * 64];
  const int mt = blockIdx.x, nt = blockIdx.y;
  const int ncols = nt ? 32 : 128;
  const int wcol0 = nt * 128;
  const u16* A = xm0f + (size_t)mt * 128 * 1024;
  const u16* B = x0wf + (size_t)wcol0 * 1024;
  const int tid = threadIdx.x;
  const int lane = tid & 63;
  const int wv = tid >> 6;
  const int wr = wv >> 1, wc = wv & 1;
  const int srow = wv * 32;
  f32x4 acc[4][4];
  #pragma unroll
  for (int i = 0; i < 4; ++i)
    #pragma unroll
    for (int j = 0; j < 4; ++j) acc[i][j] = {0.f, 0.f, 0.f, 0.f};

  for (int k0 = 0; k0 < 1024; k0 += 64) {
    #pragma unroll
    for (int c = 0; c < 4; ++c) {
      const int s8 = srow + c * 8;
      stage_swz(A, sA, s8, k0, lane);
      {
        const int rr = (s8 + (lane >> 3)) & (ncols - 1);
        const int ss = (lane & 7) ^ ((lane >> 3) & 7);
        __builtin_amdgcn_global_load_lds(
            (gu32*)(const void*)(B + (size_t)rr * 1024 + k0 + ss * 8),
            (lu32*)(void*)(sB + s8 * 64), 16, 0, 0);
      }
    }
    __syncthreads();
    #pragma unroll
    for (int kk = 0; kk < 2; ++kk) {
      const int sl = kk * 4 + (lane >> 4);
      f16x8 af[4], bf[4];
      #pragma unroll
      for (int m = 0; m < 4; ++m)
        af[m] = read_swz(sA, wr * 64 + m * 16 + (lane & 15), sl);
      #pragma unroll
      for (int j = 0; j < 4; ++j)
        bf[j] = read_swz(sB, wc * 64 + j * 16 + (lane & 15), sl);
      #pragma unroll
      for (int m = 0; m < 4; ++m)
        #pragma unroll
        for (int j = 0; j < 4; ++j)
          acc[m][j] = __builtin_amdgcn_mfma_f32_16x16x32_f16(af[m], bf[j], acc[m][j], 0, 0, 0);
    }
    __syncthreads();
  }
  #pragma unroll
  for (int m = 0; m < 4; ++m)
    #pragma unroll
    for (int r = 0; r < 4; ++r) {
      const int row = wr * 64 + m * 16 + (lane >> 4) * 4 + r;
      #pragma unroll
      for (int j = 0; j < 4; ++j) {
        const int col = wc * 64 + j * 16 + (lane & 15);
        if (col < ncols)
          t160[(size_t)(mt * 128 + row) * 160 + wcol0 + col] = tanhf(acc[m][j][r]);
      }
    }
}

// ---------------------------------------------------------------- kernel A2m5
// R28 form; epilogue branch-free (all planes f16); xmw now f16.
__global__ __launch_bounds__(256) void kA2m5(
    const float* __restrict__ t160G, const float* __restrict__ x2_w,
    const float* __restrict__ x_bias, const u16* __restrict__ xm0f,
    const u16* __restrict__ deltaf, const float* __restrict__ x0_mu,
    u16* __restrict__ xmf, u16* __restrict__ xmwH) {
  __shared__ float As[64 * 33];
  __shared__ float Ws[64 * 33];
  const int tid = threadIdx.x;
  const int n = blockIdx.x;
  const int m0 = blockIdx.y * 64, h0 = blockIdx.z * 64;
  const int rm = (tid >> 4) * 4, cn = (tid & 15) * 4;
  ushort4 xmu[4], dvu[4];
  #pragma unroll
  for (int i = 0; i < 4; ++i) {
    const size_t rowo = (size_t)(m0 + rm + i) * 1024 + h0 + cn;
    xmu[i] = *reinterpret_cast<const ushort4*>(xm0f + rowo);
    dvu[i] = *reinterpret_cast<const ushort4*>(deltaf + rowo);
  }
  const float4 mu4 = ld4(x0_mu + h0 + cn);
  const float4 b4 = ld4(x_bias + n * 1024 + h0 + cn);
  #pragma unroll
  for (int c = 0; c < 2; ++c) {
    int r = c * 32 + (tid >> 3);
    int col = (tid & 7) * 4;
    float4 a4 = ld4(t160G + (size_t)(m0 + r) * 160 + n * 32 + col);
    As[r * 33 + col + 0] = a4.x; As[r * 33 + col + 1] = a4.y;
    As[r * 33 + col + 2] = a4.z; As[r * 33 + col + 3] = a4.w;
    float4 w4 = ld4(x2_w + (size_t)(h0 + r) * 160 + n * 32 + col);
    Ws[r * 33 + col + 0] = w4.x; Ws[r * 33 + col + 1] = w4.y;
    Ws[r * 33 + col + 2] = w4.z; Ws[r * 33 + col + 3] = w4.w;
  }
  __syncthreads();
  float acc[4][4] = {};
  #pragma unroll
  for (int kk = 0; kk < 32; ++kk) {
    float a[4], w[4];
    #pragma unroll
    for (int i = 0; i < 4; ++i) a[i] = As[(rm + i) * 33 + kk];
    #pragma unroll
    for (int j = 0; j < 4; ++j) w[j] = Ws[(cn + j) * 33 + kk];
    #pragma unroll
    for (int i = 0; i < 4; ++i)
      #pragma unroll
      for (int j = 0; j < 4; ++j) acc[i][j] += a[i] * w[j];
  }
  const int pi = (n == 0) ? 0 : (n == 2) ? 1 : (n == 3) ? 2 : 3;
  u16* dstBase = (n == 1) ? xmwH : (xmf + (size_t)pi * Tc * 1024);
  #pragma unroll
  for (int i = 0; i < 4; ++i) {
    const size_t rowo = (size_t)(m0 + rm + i) * 1024 + h0 + cn;
    float4 o;
    o.x = h2f(xmu[i].x) + h2f(dvu[i].x) * (acc[i][0] + b4.x - mu4.x);
    o.y = h2f(xmu[i].y) + h2f(dvu[i].y) * (acc[i][1] + b4.y - mu4.y);
    o.z = h2f(xmu[i].z) + h2f(dvu[i].z) * (acc[i][2] + b4.z - mu4.z);
    o.w = h2f(xmu[i].w) + h2f(dvu[i].w) * (acc[i][3] + b4.w - mu4.w);
    ushort4 h;
    h.x = f2h(o.x); h.y = f2h(o.y); h.z = f2h(o.z); h.w = f2h(o.w);
    *reinterpret_cast<ushort4*>(dstBase + rowo) = h;
  }
}

// ---------------------------------------------------------------- kernel WL
// K-split x4 -> f32 partials ywp; xmw input now f16 (convert at LDS write).
__global__ __launch_bounds__(256) void kWL(
    const u16* __restrict__ xmwH, const float* __restrict__ w_w1,
    float* __restrict__ ywp) {
  __shared__ float As[32 * 33];
  __shared__ float Ws[64 * 33];
  const int tid = threadIdx.x;
  const int t0 = blockIdx.x * 32;
  const int kbase = blockIdx.y * 256;
  const int rg = tid >> 5;
  const int cg = tid & 31;
  float acc[4][2] = {};
  for (int k0 = kbase; k0 < kbase + 256; k0 += 32) {
    __syncthreads();
    {
      int r = tid >> 3, c4 = (tid & 7) * 4;
      ushort4 a4u = *reinterpret_cast<const ushort4*>(
          xmwH + (size_t)(t0 + r) * 1024 + k0 + c4);
      As[r * 33 + c4 + 0] = h2f(a4u.x); As[r * 33 + c4 + 1] = h2f(a4u.y);
      As[r * 33 + c4 + 2] = h2f(a4u.z); As[r * 33 + c4 + 3] = h2f(a4u.w);
    }
    #pragma unroll
    for (int c = 0; c < 2; ++c) {
      int r = c * 32 + (tid >> 3), c4 = (tid & 7) * 4;
      float4 w4 = ld4(w_w1 + (size_t)r * 1024 + k0 + c4);
      Ws[r * 33 + c4 + 0] = w4.x; Ws[r * 33 + c4 + 1] = w4.y;
      Ws[r * 33 + c4 + 2] = w4.z; Ws[r * 33 + c4 + 3] = w4.w;
    }
    __syncthreads();
    #pragma unroll
    for (int kk = 0; kk < 32; ++kk) {
      float a[4];
      #pragma unroll
      for (int i = 0; i < 4; ++i) a[i] = As[(rg * 4 + i) * 33 + kk];
      float w0 = Ws[cg * 33 + kk], w1 = Ws[(cg + 32) * 33 + kk];
      #pragma unroll
      for (int i = 0; i < 4; ++i) { acc[i][0] += a[i] * w0; acc[i][1] += a[i] * w1; }
    }
  }
  float* outp = ywp + (size_t)blockIdx.y * Tc * 64;
  #pragma unroll
  for (int i = 0; i < 4; ++i) {
    outp[(size_t)(t0 + rg * 4 + i) * 64 + cg]      = acc[i][0];
    outp[(size_t)(t0 + rg * 4 + i) * 64 + cg + 32] = acc[i][1];
  }
}

// ---------------------- single-pass f16 MFMA GEMM (24 tiles, all f16 out)
__global__ __launch_bounds__(256) void kB(
    const u16* __restrict__ xmf, const u16* __restrict__ Wf,
    u16* __restrict__ rG, u16* __restrict__ kG,
    u16* __restrict__ vG, u16* __restrict__ gG) {
  __shared__ __align__(16) u16 sA[128 * 64];
  __shared__ __align__(16) u16 sB[128 * 64];
  const int mt = blockIdx.x, nt = blockIdx.y;
  int plane, col0, ldc;
  u16* Ch;
  if (nt < 4)       { plane = 0; Ch = rG; ldc = 512;  col0 = nt * 128; }
  else if (nt < 8)  { plane = 1; Ch = kG; ldc = 512;  col0 = (nt - 4) * 128; }
  else if (nt < 16) { plane = 2; Ch = vG; ldc = 1024; col0 = (nt - 8) * 128; }
  else              { plane = 3; Ch = gG; ldc = 1024; col0 = (nt - 16) * 128; }
  const u16* A = xmf + ((size_t)plane * Tc + (size_t)mt * 128) * 1024;
  const u16* B = Wf + (size_t)nt * 128 * 1024;

  const int tid = threadIdx.x;
  const int lane = tid & 63;
  const int wv = tid >> 6;
  const int wr = wv >> 1, wc = wv & 1;
  const int srow = wv * 32;
  f32x4 acc[4][4];
  #pragma unroll
  for (int i = 0; i < 4; ++i)
    #pragma unroll
    for (int j = 0; j < 4; ++j) acc[i][j] = {0.f, 0.f, 0.f, 0.f};

  for (int k0 = 0; k0 < 1024; k0 += 64) {
    #pragma unroll
    for (int c = 0; c < 4; ++c) {
      const int s8 = srow + c * 8;
      stage_swz(A, sA, s8, k0, lane);
      stage_swz(B, sB, s8, k0, lane);
    }
    __syncthreads();
    #pragma unroll
    for (int kk = 0; kk < 2; ++kk) {
      const int sl = kk * 4 + (lane >> 4);
      f16x8 af[4], bf[4];
      #pragma unroll
      for (int m = 0; m < 4; ++m)
        af[m] = read_swz(sA, wr * 64 + m * 16 + (lane & 15), sl);
      #pragma unroll
      for (int j = 0; j < 4; ++j)
        bf[j] = read_swz(sB, wc * 64 + j * 16 + (lane & 15), sl);
      #pragma unroll
      for (int m = 0; m < 4; ++m)
        #pragma unroll
        for (int j = 0; j < 4; ++j)
          acc[m][j] = __builtin_amdgcn_mfma_f32_16x16x32_f16(af[m], bf[j], acc[m][j], 0, 0, 0);
    }
    __syncthreads();
  }
  #pragma unroll
  for (int m = 0; m < 4; ++m)
    #pragma unroll
    for (int r = 0; r < 4; ++r) {
      const int row = wr * 64 + m * 16 + (lane >> 4) * 4 + r;
      #pragma unroll
      for (int j = 0; j < 4; ++j) {
        const int col = wc * 64 + j * 16 + (lane & 15);
        Ch[(size_t)(mt * 128 + row) * ldc + col0 + col] = f2h(acc[m][j][r]);
      }
    }
}

// ---------------------------------------------------------------- kernel C
__global__ __launch_bounds__(256) void kC(
    const float* __restrict__ ywp, const float* __restrict__ w_w2,
    const float* __restrict__ w_b2, float* __restrict__ wfin) {
  __shared__ float th[32 * 68];
  const int tid = threadIdx.x;
  const int t0 = blockIdx.x * 32;
  for (int idx = tid; idx < 32 * 64; idx += 256) {
    int i = idx >> 6, j = idx & 63;
    const size_t e = (size_t)(t0 + i) * 64 + j;
    float s = ywp[e] + ywp[(size_t)Tc * 64 + e] +
              ywp[(size_t)2 * Tc * 64 + e] + ywp[(size_t)3 * Tc * 64 + e];
    th[i * 68 + j] = tanhf(s);
  }
  __syncthreads();
  const int c = blockIdx.y * 256 + tid;
  float acc[32] = {};
  const float* w2 = w_w2 + (size_t)c * 64;
  for (int k = 0; k < 64; k += 4) {
    float4 wv = ld4(w2 + k);
    #pragma unroll
    for (int i = 0; i < 32; ++i) {
      float4 t4 = ld4(th + i * 68 + k);
      acc[i] += t4.x * wv.x + t4.y * wv.y + t4.z * wv.z + t4.w * wv.w;
    }
  }
  const float b = w_b2[c];
  #pragma unroll
  for (int i = 0; i < 32; ++i)
    wfin[(size_t)(t0 + i) * 512 + c] = -__expf(acc[i] + b);
}

// ---------------------------------------------------------------- kernel D1
__global__ __launch_bounds__(512) void kD1(
    const u16* __restrict__ rG, const u16* __restrict__ kG,
    const u16* __restrict__ vG, const float* __restrict__ wfin,
    const float* __restrict__ bonus, u16* __restrict__ wkvG,
    float* __restrict__ decayG, u16* __restrict__ qeH, u16* __restrict__ oH) {
  __shared__ __align__(16) float smem[13632];
  float* qeT   = smem;                          // [128][33] f32
  float* kwT   = smem + 4224;                   // [128][33] f32
  u16*   vl    = (u16*)(smem + 8448);           // [32][256] u16 (16384 B)
  float* wcl   = (float*)vl;                    // [32][128] f32 alias (dead before vl)
  float* Al    = smem + 8448 + 4096;            // [32][32] f32
  float* diag2 = Al + 1024;                     // [32][2]
  const int tid = threadIdx.x;
  const int bid = blockIdx.x;
  const int nc = bid & 63, h = (bid >> 6) & 3, b = bid >> 8;
  const int tb = b * Lc + nc * 32;

  float4 wf[2];
  #pragma unroll
  for (int it = 0; it < 2; ++it) {
    int idx = it * 512 + tid;
    int c = idx >> 5, d4 = (idx & 31) * 4;
    wf[it] = ld4(wfin + (size_t)(tb + c) * 512 + h * 128 + d4);
  }
  ushort4 vreg[4];
  #pragma unroll
  for (int it = 0; it < 4; ++it) {
    int idx = it * 512 + tid;
    int c = idx >> 6, p4 = (idx & 63) * 4;
    vreg[it] = *reinterpret_cast<const ushort4*>(
        vG + (size_t)(tb + c) * 1024 + h * 256 + p4);
  }
  float rreg[8], kreg[8];
  #pragma unroll
  for (int it = 0; it < 8; ++it) {
    int idx = it * 512 + tid;
    int c = idx >> 7, d = idx & 127;
    rreg[it] = h2f(rG[(size_t)(tb + c) * 512 + h * 128 + d]);
    kreg[it] = h2f(kG[(size_t)(tb + c) * 512 + h * 128 + d]);
  }
  const float ureg = bonus[h * 128 + (tid & 127)];

  #pragma unroll
  for (int it = 0; it < 2; ++it) {
    int idx = it * 512 + tid;
    int c = idx >> 5, d4 = (idx & 31) * 4;
    st4(wcl + c * 128 + d4, wf[it]);
  }
  __syncthreads();  // B1
  if (tid < 128) {
    const int d = tid;
    float wv_[32];
    #pragma unroll
    for (int c = 0; c < 32; ++c) wv_[c] = wcl[c * 128 + d];
    float run = 0.f;
    #pragma unroll
    for (int c = 0; c < 32; ++c) { run += wv_[c]; wcl[c * 128 + d] = run; }
  }
  __syncthreads();  // B2
  #pragma unroll
  for (int it = 0; it < 8; ++it) {
    int idx = it * 512 + tid;
    int c = idx >> 7, d = idx & 127;
    int t = tb + c;
    float q = rreg[it];
    float k = kreg[it];
    float wcc = wcl[c * 128 + d];
    float wcp = (c > 0) ? wcl[(c - 1) * 128 + d] : 0.f;
    float wlast = wcl[31 * 128 + d];
    float qe = q * __expf(wcp);
    qeT[d * 33 + c] = q * __expf(wcp - wlast);
    kwT[d * 33 + c] = k * __expf(wlast - wcc);
    qeH[(size_t)t * 512 + h * 128 + d] = f2h(qe);
    if (c == 31) decayG[(size_t)bid * 128 + d] = __expf(wlast);
    float dv = q * k * ureg;
    #pragma unroll
    for (int m = 1; m < 64; m <<= 1) dv += __shfl_xor(dv, m, 64);
    if ((tid & 63) == 0) diag2[c * 2 + ((tid >> 6) & 1)] = dv;
  }
  __syncthreads();  // B3
  #pragma unroll
  for (int it = 0; it < 4; ++it) {
    int idx = it * 512 + tid;
    int c = idx >> 6, p4 = (idx & 63) * 4;
    *reinterpret_cast<ushort4*>(vl + c * 256 + p4) = vreg[it];
  }
  {
    const int j = tid & 31, i2 = tid >> 5;
    float a0 = 0.f, a1 = 0.f;
    for (int d = 0; d < 128; ++d) {
      float kv = kwT[d * 33 + j];
      a0 += qeT[d * 33 + i2] * kv;
      a1 += qeT[d * 33 + i2 + 16] * kv;
    }
    float dg0 = diag2[i2 * 2] + diag2[i2 * 2 + 1];
    float dg1 = diag2[(i2 + 16) * 2] + diag2[(i2 + 16) * 2 + 1];
    Al[i2 * 32 + j] = (j < i2) ? a0 : ((j == i2) ? dg0 : 0.f);
    Al[(i2 + 16) * 32 + j] = (j < i2 + 16) ? a1 : ((j == i2 + 16) ? dg1 : 0.f);
  }
  __syncthreads();  // B4
  const int pid = tid & 63, wvx = tid >> 6;
  const int p4 = pid * 4;
  {  // wkv -> f16
    u16* wkvB = wkvG + (size_t)bid * (128 * 256);
    #pragma unroll
    for (int pp = 0; pp < 2; ++pp) {
      const int d0 = pp * 64 + wvx * 8;
      float4 acc[8];
      #pragma unroll
      for (int q = 0; q < 8; ++q) acc[q] = make_float4(0, 0, 0, 0);
      for (int c = 0; c < 32; ++c) {
        ushort4 v4u = *reinterpret_cast<const ushort4*>(vl + c * 256 + p4);
        float vx = h2f(v4u.x), vy = h2f(v4u.y), vz = h2f(v4u.z), vw = h2f(v4u.w);
        #pragma unroll
        for (int q = 0; q < 8; ++q) {
          float s = kwT[(d0 + q) * 33 + c];
          acc[q].x += vx * s; acc[q].y += vy * s;
          acc[q].z += vz * s; acc[q].w += vw * s;
        }
      }
      #pragma unroll
      for (int q = 0; q < 8; ++q) {
        ushort4 ob;
        ob.x = f2h(acc[q].x); ob.y = f2h(acc[q].y);
        ob.z = f2h(acc[q].z); ob.w = f2h(acc[q].w);
        *reinterpret_cast<ushort4*>(wkvB + (size_t)(d0 + q) * 256 + p4) = ob;
      }
    }
  }
  {  // o_intra = A @ v  -> f16
    float4 acc[4];
    #pragma unroll
    for (int q = 0; q < 4; ++q) acc[q] = make_float4(0, 0, 0, 0);
    for (int c = 0; c < 32; ++c) {
      ushort4 v4u = *reinterpret_cast<const ushort4*>(vl + c * 256 + p4);
      float vx = h2f(v4u.x), vy = h2f(v4u.y), vz = h2f(v4u.z), vw = h2f(v4u.w);
      #pragma unroll
      for (int q = 0; q < 4; ++q) {
        float a = Al[(wvx * 4 + q) * 32 + c];
        acc[q].x += vx * a; acc[q].y += vy * a;
        acc[q].z += vz * a; acc[q].w += vw * a;
      }
    }
    #pragma unroll
    for (int q = 0; q < 4; ++q) {
      ushort4 ob;
      ob.x = f2h(acc[q].x); ob.y = f2h(acc[q].y);
      ob.z = f2h(acc[q].z); ob.w = f2h(acc[q].w);
      *reinterpret_cast<ushort4*>(
          oH + (size_t)(tb + wvx * 4 + q) * 1024 + h * 256 + p4) = ob;
    }
  }
}

// ---------------------------------------------------------------- kernel D2
__global__ __launch_bounds__(256) void kD2(u16* __restrict__ wkvG,
                                           const float* __restrict__ decayG) {
  const int wvid = (blockIdx.x * 256 + threadIdx.x) >> 6;  // 0..1023
  const int lane = threadIdx.x & 63;
  const int p4 = lane * 4;
  const int d = wvid & 127;
  const int bh = wvid >> 7;
  u16* base = wkvG + ((size_t)bh * 64 * 128 + d) * 256 + p4;
  const float* dbase = decayG + (size_t)bh * 64 * 128 + d;
  ushort4 kvb[4];
  float decb[4];
  #pragma unroll
  for (int i = 0; i < 4; ++i) {
    kvb[i] = *reinterpret_cast<const ushort4*>(base + (size_t)i * 32768);
    decb[i] = dbase[(size_t)i * 128];
  }
  float4 S = make_float4(0.f, 0.f, 0.f, 0.f);
  #pragma unroll
  for (int nc = 0; nc < 64; ++nc) {
    const int sl = nc & 3;
    ushort4 kv = kvb[sl];
    float dec = decb[sl];
    if (nc + 4 < 64) {
      kvb[sl] = *reinterpret_cast<const ushort4*>(base + (size_t)(nc + 4) * 32768);
      decb[sl] = dbase[(size_t)(nc + 4) * 128];
    }
    ushort4 ob;
    ob.x = f2h(S.x); ob.y = f2h(S.y); ob.z = f2h(S.z); ob.w = f2h(S.w);
    *reinterpret_cast<ushort4*>(base + (size_t)nc * 32768) = ob;
    S.x = S.x * dec + h2f(kv.x);
    S.y = S.y * dec + h2f(kv.y);
    S.z = S.z * dec + h2f(kv.z);
    S.w = S.w * dec + h2f(kv.w);
  }
}

// ---------------------------------------------------------------- kernel D3 (+GN+swish fused)
__global__ __launch_bounds__(256) void kD3(
    const u16* __restrict__ qeH, const u16* __restrict__ wkvG,
    const u16* __restrict__ oH, const u16* __restrict__ gG,
    const float* __restrict__ gn_w, const float* __restrict__ gn_b,
    u16* __restrict__ gate) {
  __shared__ float qel[32 * 129];
  const int tid = threadIdx.x;
  const int bid = blockIdx.x;
  const int nc = bid & 63, h = (bid >> 6) & 3, b = bid >> 8;
  const int tb = b * Lc + nc * 32;
  for (int it = 0; it < 16; ++it) {
    int idx = it * 256 + tid;
    int c = idx >> 7, d = idx & 127;
    qel[c * 129 + d] = h2f(qeH[(size_t)(tb + c) * 512 + h * 128 + d]);
  }
  __syncthreads();
  const int pid = tid & 63, wvx = tid >> 6;
  const int p4 = pid * 4;
  const int vd = h * 256 + p4;
  const float4 gw = ld4(gn_w + vd), gb = ld4(gn_b + vd);
  const u16* Sb = wkvG + (size_t)bid * (128 * 256);
  float4 acc[8];
  #pragma unroll
  for (int q = 0; q < 8; ++q) acc[q] = make_float4(0, 0, 0, 0);
  for (int d = 0; d < 128; ++d) {
    ushort4 s4 = *reinterpret_cast<const ushort4*>(Sb + (size_t)d * 256 + p4);
    float sx = h2f(s4.x), sy = h2f(s4.y), sz = h2f(s4.z), sw = h2f(s4.w);
    #pragma unroll
    for (int q = 0; q < 8; ++q) {
      float qv = qel[(wvx * 8 + q) * 129 + d];
      acc[q].x += sx * qv; acc[q].y += sy * qv;
      acc[q].z += sz * qv; acc[q].w += sw * qv;
    }
  }
  #pragma unroll
  for (int q = 0; q < 8; ++q) {
    const int t = tb + wvx * 8 + q;
    ushort4 c4 = *reinterpret_cast<const ushort4*>(oH + (size_t)t * 1024 + vd);
    float4 o4;
    o4.x = h2f(c4.x) + acc[q].x; o4.y = h2f(c4.y) + acc[q].y;
    o4.z = h2f(c4.z) + acc[q].z; o4.w = h2f(c4.w) + acc[q].w;
    float s = o4.x + o4.y + o4.z + o4.w;
    float ss = o4.x * o4.x + o4.y * o4.y + o4.z * o4.z + o4.w * o4.w;
    #pragma unroll
    for (int m = 1; m < 64; m <<= 1) {
      s += __shfl_xor(s, m, 64);
      ss += __shfl_xor(ss, m, 64);
    }
    const float mean = s * (1.f / 256.f);
    const float var = ss * (1.f / 256.f) - mean * mean;
    const float rs = rsqrtf(var + 1e-5f);
    float4 on;
    on.x = (o4.x - mean) * rs * gw.x + gb.x;
    on.y = (o4.y - mean) * rs * gw.y + gb.y;
    on.z = (o4.z - mean) * rs * gw.z + gb.z;
    on.w = (o4.w - mean) * rs * gw.w + gb.w;
    ushort4 g4 = *reinterpret_cast<const ushort4*>(gG + (size_t)t * 1024 + vd);
    float gx = h2f(g4.x), gy = h2f(g4.y), gz = h2f(g4.z), gw_ = h2f(g4.w);
    float4 sw;
    sw.x = gx / (1.f + __expf(-gx));
    sw.y = gy / (1.f + __expf(-gy));
    sw.z = gz / (1.f + __expf(-gz));
    sw.w = gw_ / (1.f + __expf(-gw_));
    ushort4 ob;
    ob.x = f2h(on.x * sw.x); ob.y = f2h(on.y * sw.y);
    ob.z = f2h(on.z * sw.z); ob.w = f2h(on.w * sw.w);
    *reinterpret_cast<ushort4*>(gate + (size_t)t * 1024 + vd) = ob;
  }
}

// ---------------------------------------------------------------- kernel F (f16)
__global__ __launch_bounds__(256) void kF(
    const u16* __restrict__ gate, const u16* __restrict__ owb,
    float* __restrict__ out) {
  __shared__ __align__(16) u16 Abuf[128 * 64];
  __shared__ __align__(16) u16 Bbuf[128 * 64];
  const int mt = blockIdx.x, nt = blockIdx.y;
  const u16* A = gate + (size_t)mt * 128 * 1024;
  const u16* W = owb + (size_t)nt * 128 * 1024;
  float* C = out + (size_t)mt * 128 * 1024 + nt * 128;
  const int tid = threadIdx.x;
  const int lane = tid & 63;
  const int wv = tid >> 6;
  const int wr = wv >> 1, wc = wv & 1;
  const int srow = wv * 32;
  f32x4 acc[4][4];
  #pragma unroll
  for (int i = 0; i < 4; ++i)
    #pragma unroll
    for (int j = 0; j < 4; ++j) acc[i][j] = {0.f, 0.f, 0.f, 0.f};
  for (int k0 = 0; k0 < 1024; k0 += 64) {
    #pragma unroll
    for (int c = 0; c < 4; ++c) {
      const int s8 = srow + c * 8;
      stage_swz(A, Abuf, s8, k0, lane);
      stage_swz(W, Bbuf, s8, k0, lane);
    }
    __syncthreads();
    #pragma unroll
    for (int kk = 0; kk < 2; ++kk) {
      const int sl = kk * 4 + (lane >> 4);
      f16x8 af[4], bf[4];
      #pragma unroll
      for (int m = 0; m < 4; ++m)
        af[m] = read_swz(Abuf, wr * 64 + m * 16 + (lane & 15), sl);
      #pragma unroll
      for (int j = 0; j < 4; ++j)
        bf[j] = read_swz(Bbuf, wc * 64 + j * 16 + (lane & 15), sl);
      #pragma unroll
      for (int m = 0; m < 4; ++m)
        #pragma unroll
        for (int j = 0; j < 4; ++j)
          acc[m][j] = __builtin_amdgcn_mfma_f32_16x16x32_f16(af[m], bf[j], acc[m][j], 0, 0, 0);
    }
    __syncthreads();
  }
  #pragma unroll
  for (int m = 0; m < 4; ++m)
    #pragma unroll
    for (int r = 0; r < 4; ++r) {
      const int row = wr * 64 + m * 16 + (lane >> 4) * 4 + r;
      #pragma unroll
      for (int j = 0; j < 4; ++j) {
        const int col = wc * 64 + j * 16 + (lane & 15);
        C[(size_t)row * 1024 + col] = acc[m][j][r];
      }
    }
}

}  // namespace

extern "C" void kernel_launch(void* const* d_in, const int* in_sizes, int n_in,
                              void* d_out, int out_size, void* d_ws, size_t ws_size,
                              hipStream_t stream) {
  (void)in_sizes; (void)n_in; (void)out_size;
  if (ws_size < WS_NEED) return;

  const float* x      = (const float*)d_in[0];
  const float* x0_mu  = (const float*)d_in[1];
  const float* x0_w   = (const float*)d_in[2];
  const float* x2_w   = (const float*)d_in[3];
  const float* x_bias = (const float*)d_in[4];
  const float* r_w    = (const float*)d_in[5];
  const float* w_w1   = (const float*)d_in[6];
  const float* w_w2   = (const float*)d_in[7];
  const float* w_b2   = (const float*)d_in[8];
  const float* k_w    = (const float*)d_in[9];
  const float* v_w    = (const float*)d_in[10];
  const float* g_w    = (const float*)d_in[11];
  const float* bonus  = (const float*)d_in[12];
  const float* gn_w   = (const float*)d_in[13];
  const float* gn_b   = (const float*)d_in[14];
  const float* o_w    = (const float*)d_in[15];
  float* out = (float*)d_out;
  char* ws = (char*)d_ws;

  u16*   wkvG   = (u16*)(ws + OFF_WKV);
  u16*   xm0f   = (u16*)(ws + OFF_XM0F);
  u16*   deltaf = (u16*)(ws + OFF_DELTAF);
  float* t160   = (float*)(ws + OFF_T160);
  u16*   xmwH   = (u16*)(ws + OFF_XMW);
  u16*   x0wf   = (u16*)(ws + OFF_X0WF);
  float* ywp    = (float*)(ws + OFF_YWP);
  u16*   xmf    = (u16*)(ws + OFF_XMF);
  float* wfin   = (float*)(ws + OFF_WFIN);
  u16*   gate   = (u16*)(ws + OFF_GATE);
  u16*   qeH    = (u16*)(ws + OFF_QE);
  u16*   oH     = (u16*)(ws + OFF_OO);
  u16*   Wf     = (u16*)(ws + OFF_WF);
  float* decayG = (float*)(ws + OFF_DECAY);
  u16*   owb    = (u16*)(ws + OFF_OWB);
  u16*   rG     = (u16*)(ws + OFF_RG);
  u16*   kG     = (u16*)(ws + OFF_KG);
  u16*   vG     = (u16*)(ws + OFF_VG);
  u16*   gG     = (u16*)(ws + OFF_GG);

  kWA  <<<dim3(8352),        dim3(256), 0, stream>>>(r_w, k_w, v_w, g_w, o_w, x0_w,
                                                     x, x0_mu, Wf, owb, x0wf,
                                                     xm0f, deltaf);
  kA2f <<<dim3(32, 2),       dim3(256), 0, stream>>>(xm0f, x0wf, t160);
  kA2m5<<<dim3(5, 64, 16),   dim3(256), 0, stream>>>(t160, x2_w, x_bias, xm0f,
                                                     deltaf, x0_mu, xmf, xmwH);
  kWL  <<<dim3(128, 4),      dim3(256), 0, stream>>>(xmwH, w_w1, ywp);
  kB   <<<dim3(32, 24),      dim3(256), 0, stream>>>(xmf, Wf, rG, kG, vG, gG);
  kC   <<<dim3(128, 2),      dim3(256), 0, stream>>>(ywp, w_w2, w_b2, wfin);
  kD1  <<<dim3(512),         dim3(512), 0, stream>>>(rG, kG, vG, wfin, bonus,
                                                     wkvG, decayG, qeH, oH);
  kD2  <<<dim3(256),         dim3(256), 0, stream>>>(wkvG, decayG);
  kD3  <<<dim3(512),         dim3(256), 0, stream>>>(qeH, wkvG, oH, gG,
                                                     gn_w, gn_b, gate);
  kF   <<<dim3(32, 8),       dim3(256), 0, stream>>>(gate, owb, out);
}

// Round 30
// 261.627 us; speedup vs baseline: 1.0662x; 1.0662x over previous
//
#include <hip/hip_runtime.h>

// RWKV6Attention forward — round 30: exact R28 configuration (best measured:
// 262.3us, absmax 1.208e-2). R29's xmw-f16 touch to kA2m5 blew VGPR 104->156
// (4th kA2m5 codegen tarpit) and is reverted. Final configuration:
// f16 MFMA GEMMs (kA2f/kB/kF), f16 r/k/v/g/wkv/qe/o_intra/xm0/delta seams,
// f32 w-path (wfin/xmw/ywp), fused GN+swish in kD3, 3-blocks/CU kD1.

#define DEVI __device__ __forceinline__

namespace {

typedef unsigned short u16;
typedef unsigned int u32;
typedef __attribute__((ext_vector_type(8))) _Float16 f16x8;  // 4 VGPRs
typedef __attribute__((ext_vector_type(4))) float f32x4;

typedef __attribute__((address_space(1))) const u32 gu32;
typedef __attribute__((address_space(3))) u32 lu32;

constexpr int Lc = 2048;
constexpr int Tc = 4096;   // B*L

// ---- workspace layout (byte offsets), lifetime-safe aliasing.
constexpr size_t OFF_WKV    = 0;           // f16 [512][128][256] (kD1+)
constexpr size_t OFF_XM0F   = 0;           //   f16 [T][1024] (kWA -> kA2f/kA2m5, dead before kD1)
constexpr size_t OFF_DELTAF = 16777216;    //   f16 [T][1024] (kWA -> kA2m5, dead before kD1)
constexpr size_t OFF_T160   = 33554432;    // f32 [T][160]  dead after kA2m5
constexpr size_t OFF_XMW    = 36175872;    // f32 [T][1024] (kA2m5 -> kWL)
constexpr size_t OFF_X0WF   = 54001664;    // f16 [160][1024]
constexpr size_t OFF_YWP    = 56623104;    // f32 [4][T][64] (kWL -> kC)
constexpr size_t OFF_XMF    = 67108864;    // f16 [4][T][1024] (kA2m5 -> kB)
constexpr size_t OFF_WFIN   = 67108864;    //   f32 [T][512]  (kC -> kD1, after kB)
constexpr size_t OFF_GATE   = 75497472;    //   f16 [T][1024] (kD3 -> kF)
constexpr size_t OFF_QE     = 100663296;   // f16 [T][512] (kD1 -> kD3)
constexpr size_t OFF_OO     = 109051904;   // f16 [T][1024] o_intra (kD1 -> kD3)
constexpr size_t OFF_WF     = 125829120;   // f16 [3072][1024]
constexpr size_t OFF_DECAY  = 132120576;
constexpr size_t OFF_OWB    = 136314880;   // f16 [1024][1024]
constexpr size_t OFF_RG     = 138412032;   // f16 [T][512]
constexpr size_t OFF_KG     = 146800640;   // f16 [T][512]
constexpr size_t OFF_VG     = 155189248;   // f16 [T][1024]
constexpr size_t OFF_GG     = 171966464;   // f16 [T][1024]
constexpr size_t WS_NEED    = 180355072;

DEVI float4 ld4(const float* p) { return *reinterpret_cast<const float4*>(p); }
DEVI void   st4(float* p, float4 v) { *reinterpret_cast<float4*>(p) = v; }
DEVI u16 f2h(float f) { _Float16 h = (_Float16)f; return *(u16*)&h; }
DEVI float h2f(u16 u) { _Float16 h = *(_Float16*)&u; return (float)h; }

// ---- BK=64 swizzled staging (source-side XOR; linear LDS dest)
DEVI void stage_swz(const u16* __restrict__ src, u16* __restrict__ dstBase,
                    int srow8, int k0, int lane) {
  const int rr = srow8 + (lane >> 3);
  const int ss = (lane & 7) ^ ((lane >> 3) & 7);
  __builtin_amdgcn_global_load_lds(
      (gu32*)(const void*)(src + (size_t)rr * 1024 + k0 + ss * 8),
      (lu32*)(void*)(dstBase + srow8 * 64), 16, 0, 0);
}
DEVI f16x8 read_swz(const u16* __restrict__ buf, int row, int slot_lin) {
  return *reinterpret_cast<const f16x8*>(buf + row * 64 + ((slot_lin ^ (row & 7)) * 8));
}

// ---------------------------------------------------------------- kernel WA
__global__ void kWA(const float* __restrict__ r_w, const float* __restrict__ k_w,
                    const float* __restrict__ v_w, const float* __restrict__ g_w,
                    const float* __restrict__ o_w, const float* __restrict__ x0_w,
                    const float* __restrict__ x, const float* __restrict__ x0_mu,
                    u16* __restrict__ Wf, u16* __restrict__ owb,
                    u16* __restrict__ x0wf, u16* __restrict__ xm0f,
                    u16* __restrict__ deltaf) {
  if (blockIdx.x < 4256) {
    const size_t i = ((size_t)blockIdx.x * 256 + threadIdx.x) * 4;
    const float* src;
    u16* dst;
    if (i < 3145728) {
      src = (i < 524288)  ? r_w + i
          : (i < 1048576) ? k_w + (i - 524288)
          : (i < 2097152) ? v_w + (i - 1048576)
                          : g_w + (i - 2097152);
      dst = Wf + i;
    } else if (i < 4194304) {
      src = o_w + (i - 3145728);
      dst = owb + (i - 3145728);
    } else {
      src = x0_w + (i - 4194304);
      dst = x0wf + (i - 4194304);
    }
    float4 v = ld4(src);
    ushort4 h;
    h.x = f2h(v.x); h.y = f2h(v.y); h.z = f2h(v.z); h.w = f2h(v.w);
    *reinterpret_cast<ushort4*>(dst) = h;
  } else {
    const size_t i4 = (size_t)(blockIdx.x - 4256) * 256 + threadIdx.x;
    const int t = (int)(i4 >> 8);
    const int h4 = (int)(i4 & 255) * 4;
    float4 xv = ld4(x + (size_t)t * 1024 + h4);
    float4 xp = make_float4(0.f, 0.f, 0.f, 0.f);
    if (t & (Lc - 1)) xp = ld4(x + (size_t)(t - 1) * 1024 + h4);
    float4 mu = ld4(x0_mu + h4);
    float4 d;
    d.x = xp.x - xv.x; d.y = xp.y - xv.y; d.z = xp.z - xv.z; d.w = xp.w - xv.w;
    ushort4 dh;
    dh.x = f2h(d.x); dh.y = f2h(d.y); dh.z = f2h(d.z); dh.w = f2h(d.w);
    *reinterpret_cast<ushort4*>(deltaf + (size_t)t * 1024 + h4) = dh;
    float4 m0;
    m0.x = xv.x + d.x * mu.x; m0.y = xv.y + d.y * mu.y;
    m0.z = xv.z + d.z * mu.z; m0.w = xv.w + d.w * mu.w;
    ushort4 h;
    h.x = f2h(m0.x); h.y = f2h(m0.y); h.z = f2h(m0.z); h.w = f2h(m0.w);
    *reinterpret_cast<ushort4*>(xm0f + (size_t)t * 1024 + h4) = h;
  }
}

// ---------------------------------------------------------------- kernel A2f
__global__ __launch_bounds__(256) void kA2f(
    const u16* __restrict__ xm0f, const u16* __restrict__ x0wf,
    float* __restrict__ t160) {
  __shared__ __align__(16) u16 sA[128 * 64];
  __shared__ __align__(16) u16 sB[128 * 64];
  const int mt = blockIdx.x, nt = blockIdx.y;
  const int ncols = nt ? 32 : 128;
  const int wcol0 = nt * 128;
  const u16* A = xm0f + (size_t)mt * 128 * 1024;
  const u16* B = x0wf + (size_t)wcol0 * 1024;
  const int tid = threadIdx.x;
  const int lane = tid & 63;
  const int wv = tid >> 6;
  const int wr = wv >> 1, wc = wv & 1;
  const int srow = wv * 32;
  f32x4 acc[4][4];
  #pragma unroll
  for (int i = 0; i < 4; ++i)
    #pragma unroll
    for (int j = 0; j < 4; ++j) acc[i][j] = {0.f, 0.f, 0.f, 0.f};

  for (int k0 = 0; k0 < 1024; k0 += 64) {
    #pragma unroll
    for (int c = 0; c < 4; ++c) {
      const int s8 = srow + c * 8;
      stage_swz(A, sA, s8, k0, lane);
      {
        const int rr = (s8 + (lane >> 3)) & (ncols - 1);
        const int ss = (lane & 7) ^ ((lane >> 3) & 7);
        __builtin_amdgcn_global_load_lds(
            (gu32*)(const void*)(B + (size_t)rr * 1024 + k0 + ss * 8),
            (lu32*)(void*)(sB + s8 * 64), 16, 0, 0);
      }
    }
    __syncthreads();
    #pragma unroll
    for (int kk = 0; kk < 2; ++kk) {
      const int sl = kk * 4 + (lane >> 4);
      f16x8 af[4], bf[4];
      #pragma unroll
      for (int m = 0; m < 4; ++m)
        af[m] = read_swz(sA, wr * 64 + m * 16 + (lane & 15), sl);
      #pragma unroll
      for (int j = 0; j < 4; ++j)
        bf[j] = read_swz(sB, wc * 64 + j * 16 + (lane & 15), sl);
      #pragma unroll
      for (int m = 0; m < 4; ++m)
        #pragma unroll
        for (int j = 0; j < 4; ++j)
          acc[m][j] = __builtin_amdgcn_mfma_f32_16x16x32_f16(af[m], bf[j], acc[m][j], 0, 0, 0);
    }
    __syncthreads();
  }
  #pragma unroll
  for (int m = 0; m < 4; ++m)
    #pragma unroll
    for (int r = 0; r < 4; ++r) {
      const int row = wr * 64 + m * 16 + (lane >> 4) * 4 + r;
      #pragma unroll
      for (int j = 0; j < 4; ++j) {
        const int col = wc * 64 + j * 16 + (lane & 15);
        if (col < ncols)
          t160[(size_t)(mt * 128 + row) * 160 + wcol0 + col] = tanhf(acc[m][j][r]);
      }
    }
}

// ---------------------------------------------------------------- kernel A2m5
// R25 form; front-loads ushort4 (f16); xmw stays f32 (R29's f16 touch blew VGPR).
__global__ __launch_bounds__(256) void kA2m5(
    const float* __restrict__ t160G, const float* __restrict__ x2_w,
    const float* __restrict__ x_bias, const u16* __restrict__ xm0f,
    const u16* __restrict__ deltaf, const float* __restrict__ x0_mu,
    u16* __restrict__ xmf, float* __restrict__ xmw) {
  __shared__ float As[64 * 33];
  __shared__ float Ws[64 * 33];
  const int tid = threadIdx.x;
  const int n = blockIdx.x;
  const int m0 = blockIdx.y * 64, h0 = blockIdx.z * 64;
  const int rm = (tid >> 4) * 4, cn = (tid & 15) * 4;
  ushort4 xmu[4], dvu[4];
  #pragma unroll
  for (int i = 0; i < 4; ++i) {
    const size_t rowo = (size_t)(m0 + rm + i) * 1024 + h0 + cn;
    xmu[i] = *reinterpret_cast<const ushort4*>(xm0f + rowo);
    dvu[i] = *reinterpret_cast<const ushort4*>(deltaf + rowo);
  }
  const float4 mu4 = ld4(x0_mu + h0 + cn);
  const float4 b4 = ld4(x_bias + n * 1024 + h0 + cn);
  #pragma unroll
  for (int c = 0; c < 2; ++c) {
    int r = c * 32 + (tid >> 3);
    int col = (tid & 7) * 4;
    float4 a4 = ld4(t160G + (size_t)(m0 + r) * 160 + n * 32 + col);
    As[r * 33 + col + 0] = a4.x; As[r * 33 + col + 1] = a4.y;
    As[r * 33 + col + 2] = a4.z; As[r * 33 + col + 3] = a4.w;
    float4 w4 = ld4(x2_w + (size_t)(h0 + r) * 160 + n * 32 + col);
    Ws[r * 33 + col + 0] = w4.x; Ws[r * 33 + col + 1] = w4.y;
    Ws[r * 33 + col + 2] = w4.z; Ws[r * 33 + col + 3] = w4.w;
  }
  __syncthreads();
  float acc[4][4] = {};
  #pragma unroll
  for (int kk = 0; kk < 32; ++kk) {
    float a[4], w[4];
    #pragma unroll
    for (int i = 0; i < 4; ++i) a[i] = As[(rm + i) * 33 + kk];
    #pragma unroll
    for (int j = 0; j < 4; ++j) w[j] = Ws[(cn + j) * 33 + kk];
    #pragma unroll
    for (int i = 0; i < 4; ++i)
      #pragma unroll
      for (int j = 0; j < 4; ++j) acc[i][j] += a[i] * w[j];
  }
  const int pi = (n == 0) ? 0 : (n == 2) ? 1 : (n == 3) ? 2 : 3;
  #pragma unroll
  for (int i = 0; i < 4; ++i) {
    const size_t rowo = (size_t)(m0 + rm + i) * 1024 + h0 + cn;
    float4 o;
    o.x = h2f(xmu[i].x) + h2f(dvu[i].x) * (acc[i][0] + b4.x - mu4.x);
    o.y = h2f(xmu[i].y) + h2f(dvu[i].y) * (acc[i][1] + b4.y - mu4.y);
    o.z = h2f(xmu[i].z) + h2f(dvu[i].z) * (acc[i][2] + b4.z - mu4.z);
    o.w = h2f(xmu[i].w) + h2f(dvu[i].w) * (acc[i][3] + b4.w - mu4.w);
    if (n == 1) {
      st4(xmw + rowo, o);
    } else {
      ushort4 h;
      h.x = f2h(o.x); h.y = f2h(o.y); h.z = f2h(o.z); h.w = f2h(o.w);
      *reinterpret_cast<ushort4*>(xmf + (size_t)pi * Tc * 1024 + rowo) = h;
    }
  }
}

// ---------------------------------------------------------------- kernel WL
__global__ __launch_bounds__(256) void kWL(
    const float* __restrict__ xmw, const float* __restrict__ w_w1,
    float* __restrict__ ywp) {
  __shared__ float As[32 * 33];
  __shared__ float Ws[64 * 33];
  const int tid = threadIdx.x;
  const int t0 = blockIdx.x * 32;
  const int kbase = blockIdx.y * 256;
  const int rg = tid >> 5;
  const int cg = tid & 31;
  float acc[4][2] = {};
  for (int k0 = kbase; k0 < kbase + 256; k0 += 32) {
    __syncthreads();
    {
      int r = tid >> 3, c4 = (tid & 7) * 4;
      float4 a4 = ld4(xmw + (size_t)(t0 + r) * 1024 + k0 + c4);
      As[r * 33 + c4 + 0] = a4.x; As[r * 33 + c4 + 1] = a4.y;
      As[r * 33 + c4 + 2] = a4.z; As[r * 33 + c4 + 3] = a4.w;
    }
    #pragma unroll
    for (int c = 0; c < 2; ++c) {
      int r = c * 32 + (tid >> 3), c4 = (tid & 7) * 4;
      float4 w4 = ld4(w_w1 + (size_t)r * 1024 + k0 + c4);
      Ws[r * 33 + c4 + 0] = w4.x; Ws[r * 33 + c4 + 1] = w4.y;
      Ws[r * 33 + c4 + 2] = w4.z; Ws[r * 33 + c4 + 3] = w4.w;
    }
    __syncthreads();
    #pragma unroll
    for (int kk = 0; kk < 32; ++kk) {
      float a[4];
      #pragma unroll
      for (int i = 0; i < 4; ++i) a[i] = As[(rg * 4 + i) * 33 + kk];
      float w0 = Ws[cg * 33 + kk], w1 = Ws[(cg + 32) * 33 + kk];
      #pragma unroll
      for (int i = 0; i < 4; ++i) { acc[i][0] += a[i] * w0; acc[i][1] += a[i] * w1; }
    }
  }
  float* outp = ywp + (size_t)blockIdx.y * Tc * 64;
  #pragma unroll
  for (int i = 0; i < 4; ++i) {
    outp[(size_t)(t0 + rg * 4 + i) * 64 + cg]      = acc[i][0];
    outp[(size_t)(t0 + rg * 4 + i) * 64 + cg + 32] = acc[i][1];
  }
}

// ---------------------- single-pass f16 MFMA GEMM (24 tiles, all f16 out)
__global__ __launch_bounds__(256) void kB(
    const u16* __restrict__ xmf, const u16* __restrict__ Wf,
    u16* __restrict__ rG, u16* __restrict__ kG,
    u16* __restrict__ vG, u16* __restrict__ gG) {
  __shared__ __align__(16) u16 sA[128 * 64];
  __shared__ __align__(16) u16 sB[128 * 64];
  const int mt = blockIdx.x, nt = blockIdx.y;
  int plane, col0, ldc;
  u16* Ch;
  if (nt < 4)       { plane = 0; Ch = rG; ldc = 512;  col0 = nt * 128; }
  else if (nt < 8)  { plane = 1; Ch = kG; ldc = 512;  col0 = (nt - 4) * 128; }
  else if (nt < 16) { plane = 2; Ch = vG; ldc = 1024; col0 = (nt - 8) * 128; }
  else              { plane = 3; Ch = gG; ldc = 1024; col0 = (nt - 16) * 128; }
  const u16* A = xmf + ((size_t)plane * Tc + (size_t)mt * 128) * 1024;
  const u16* B = Wf + (size_t)nt * 128 * 1024;

  const int tid = threadIdx.x;
  const int lane = tid & 63;
  const int wv = tid >> 6;
  const int wr = wv >> 1, wc = wv & 1;
  const int srow = wv * 32;
  f32x4 acc[4][4];
  #pragma unroll
  for (int i = 0; i < 4; ++i)
    #pragma unroll
    for (int j = 0; j < 4; ++j) acc[i][j] = {0.f, 0.f, 0.f, 0.f};

  for (int k0 = 0; k0 < 1024; k0 += 64) {
    #pragma unroll
    for (int c = 0; c < 4; ++c) {
      const int s8 = srow + c * 8;
      stage_swz(A, sA, s8, k0, lane);
      stage_swz(B, sB, s8, k0, lane);
    }
    __syncthreads();
    #pragma unroll
    for (int kk = 0; kk < 2; ++kk) {
      const int sl = kk * 4 + (lane >> 4);
      f16x8 af[4], bf[4];
      #pragma unroll
      for (int m = 0; m < 4; ++m)
        af[m] = read_swz(sA, wr * 64 + m * 16 + (lane & 15), sl);
      #pragma unroll
      for (int j = 0; j < 4; ++j)
        bf[j] = read_swz(sB, wc * 64 + j * 16 + (lane & 15), sl);
      #pragma unroll
      for (int m = 0; m < 4; ++m)
        #pragma unroll
        for (int j = 0; j < 4; ++j)
          acc[m][j] = __builtin_amdgcn_mfma_f32_16x16x32_f16(af[m], bf[j], acc[m][j], 0, 0, 0);
    }
    __syncthreads();
  }
  #pragma unroll
  for (int m = 0; m < 4; ++m)
    #pragma unroll
    for (int r = 0; r < 4; ++r) {
      const int row = wr * 64 + m * 16 + (lane >> 4) * 4 + r;
      #pragma unroll
      for (int j = 0; j < 4; ++j) {
        const int col = wc * 64 + j * 16 + (lane & 15);
        Ch[(size_t)(mt * 128 + row) * ldc + col0 + col] = f2h(acc[m][j][r]);
      }
    }
}

// ---------------------------------------------------------------- kernel C
__global__ __launch_bounds__(256) void kC(
    const float* __restrict__ ywp, const float* __restrict__ w_w2,
    const float* __restrict__ w_b2, float* __restrict__ wfin) {
  __shared__ float th[32 * 68];
  const int tid = threadIdx.x;
  const int t0 = blockIdx.x * 32;
  for (int idx = tid; idx < 32 * 64; idx += 256) {
    int i = idx >> 6, j = idx & 63;
    const size_t e = (size_t)(t0 + i) * 64 + j;
    float s = ywp[e] + ywp[(size_t)Tc * 64 + e] +
              ywp[(size_t)2 * Tc * 64 + e] + ywp[(size_t)3 * Tc * 64 + e];
    th[i * 68 + j] = tanhf(s);
  }
  __syncthreads();
  const int c = blockIdx.y * 256 + tid;
  float acc[32] = {};
  const float* w2 = w_w2 + (size_t)c * 64;
  for (int k = 0; k < 64; k += 4) {
    float4 wv = ld4(w2 + k);
    #pragma unroll
    for (int i = 0; i < 32; ++i) {
      float4 t4 = ld4(th + i * 68 + k);
      acc[i] += t4.x * wv.x + t4.y * wv.y + t4.z * wv.z + t4.w * wv.w;
    }
  }
  const float b = w_b2[c];
  #pragma unroll
  for (int i = 0; i < 32; ++i)
    wfin[(size_t)(t0 + i) * 512 + c] = -__expf(acc[i] + b);
}

// ---------------------------------------------------------------- kernel D1
__global__ __launch_bounds__(512) void kD1(
    const u16* __restrict__ rG, const u16* __restrict__ kG,
    const u16* __restrict__ vG, const float* __restrict__ wfin,
    const float* __restrict__ bonus, u16* __restrict__ wkvG,
    float* __restrict__ decayG, u16* __restrict__ qeH, u16* __restrict__ oH) {
  __shared__ __align__(16) float smem[13632];
  float* qeT   = smem;                          // [128][33] f32
  float* kwT   = smem + 4224;                   // [128][33] f32
  u16*   vl    = (u16*)(smem + 8448);           // [32][256] u16 (16384 B)
  float* wcl   = (float*)vl;                    // [32][128] f32 alias (dead before vl)
  float* Al    = smem + 8448 + 4096;            // [32][32] f32
  float* diag2 = Al + 1024;                     // [32][2]
  const int tid = threadIdx.x;
  const int bid = blockIdx.x;
  const int nc = bid & 63, h = (bid >> 6) & 3, b = bid >> 8;
  const int tb = b * Lc + nc * 32;

  float4 wf[2];
  #pragma unroll
  for (int it = 0; it < 2; ++it) {
    int idx = it * 512 + tid;
    int c = idx >> 5, d4 = (idx & 31) * 4;
    wf[it] = ld4(wfin + (size_t)(tb + c) * 512 + h * 128 + d4);
  }
  ushort4 vreg[4];
  #pragma unroll
  for (int it = 0; it < 4; ++it) {
    int idx = it * 512 + tid;
    int c = idx >> 6, p4 = (idx & 63) * 4;
    vreg[it] = *reinterpret_cast<const ushort4*>(
        vG + (size_t)(tb + c) * 1024 + h * 256 + p4);
  }
  float rreg[8], kreg[8];
  #pragma unroll
  for (int it = 0; it < 8; ++it) {
    int idx = it * 512 + tid;
    int c = idx >> 7, d = idx & 127;
    rreg[it] = h2f(rG[(size_t)(tb + c) * 512 + h * 128 + d]);
    kreg[it] = h2f(kG[(size_t)(tb + c) * 512 + h * 128 + d]);
  }
  const float ureg = bonus[h * 128 + (tid & 127)];

  #pragma unroll
  for (int it = 0; it < 2; ++it) {
    int idx = it * 512 + tid;
    int c = idx >> 5, d4 = (idx & 31) * 4;
    st4(wcl + c * 128 + d4, wf[it]);
  }
  __syncthreads();  // B1
  if (tid < 128) {
    const int d = tid;
    float wv_[32];
    #pragma unroll
    for (int c = 0; c < 32; ++c) wv_[c] = wcl[c * 128 + d];
    float run = 0.f;
    #pragma unroll
    for (int c = 0; c < 32; ++c) { run += wv_[c]; wcl[c * 128 + d] = run; }
  }
  __syncthreads();  // B2
  #pragma unroll
  for (int it = 0; it < 8; ++it) {
    int idx = it * 512 + tid;
    int c = idx >> 7, d = idx & 127;
    int t = tb + c;
    float q = rreg[it];
    float k = kreg[it];
    float wcc = wcl[c * 128 + d];
    float wcp = (c > 0) ? wcl[(c - 1) * 128 + d] : 0.f;
    float wlast = wcl[31 * 128 + d];
    float qe = q * __expf(wcp);
    qeT[d * 33 + c] = q * __expf(wcp - wlast);
    kwT[d * 33 + c] = k * __expf(wlast - wcc);
    qeH[(size_t)t * 512 + h * 128 + d] = f2h(qe);
    if (c == 31) decayG[(size_t)bid * 128 + d] = __expf(wlast);
    float dv = q * k * ureg;
    #pragma unroll
    for (int m = 1; m < 64; m <<= 1) dv += __shfl_xor(dv, m, 64);
    if ((tid & 63) == 0) diag2[c * 2 + ((tid >> 6) & 1)] = dv;
  }
  __syncthreads();  // B3
  #pragma unroll
  for (int it = 0; it < 4; ++it) {
    int idx = it * 512 + tid;
    int c = idx >> 6, p4 = (idx & 63) * 4;
    *reinterpret_cast<ushort4*>(vl + c * 256 + p4) = vreg[it];
  }
  {
    const int j = tid & 31, i2 = tid >> 5;
    float a0 = 0.f, a1 = 0.f;
    for (int d = 0; d < 128; ++d) {
      float kv = kwT[d * 33 + j];
      a0 += qeT[d * 33 + i2] * kv;
      a1 += qeT[d * 33 + i2 + 16] * kv;
    }
    float dg0 = diag2[i2 * 2] + diag2[i2 * 2 + 1];
    float dg1 = diag2[(i2 + 16) * 2] + diag2[(i2 + 16) * 2 + 1];
    Al[i2 * 32 + j] = (j < i2) ? a0 : ((j == i2) ? dg0 : 0.f);
    Al[(i2 + 16) * 32 + j] = (j < i2 + 16) ? a1 : ((j == i2 + 16) ? dg1 : 0.f);
  }
  __syncthreads();  // B4
  const int pid = tid & 63, wvx = tid >> 6;
  const int p4 = pid * 4;
  {  // wkv -> f16
    u16* wkvB = wkvG + (size_t)bid * (128 * 256);
    #pragma unroll
    for (int pp = 0; pp < 2; ++pp) {
      const int d0 = pp * 64 + wvx * 8;
      float4 acc[8];
      #pragma unroll
      for (int q = 0; q < 8; ++q) acc[q] = make_float4(0, 0, 0, 0);
      for (int c = 0; c < 32; ++c) {
        ushort4 v4u = *reinterpret_cast<const ushort4*>(vl + c * 256 + p4);
        float vx = h2f(v4u.x), vy = h2f(v4u.y), vz = h2f(v4u.z), vw = h2f(v4u.w);
        #pragma unroll
        for (int q = 0; q < 8; ++q) {
          float s = kwT[(d0 + q) * 33 + c];
          acc[q].x += vx * s; acc[q].y += vy * s;
          acc[q].z += vz * s; acc[q].w += vw * s;
        }
      }
      #pragma unroll
      for (int q = 0; q < 8; ++q) {
        ushort4 ob;
        ob.x = f2h(acc[q].x); ob.y = f2h(acc[q].y);
        ob.z = f2h(acc[q].z); ob.w = f2h(acc[q].w);
        *reinterpret_cast<ushort4*>(wkvB + (size_t)(d0 + q) * 256 + p4) = ob;
      }
    }
  }
  {  // o_intra = A @ v  -> f16
    float4 acc[4];
    #pragma unroll
    for (int q = 0; q < 4; ++q) acc[q] = make_float4(0, 0, 0, 0);
    for (int c = 0; c < 32; ++c) {
      ushort4 v4u = *reinterpret_cast<const ushort4*>(vl + c * 256 + p4);
      float vx = h2f(v4u.x), vy = h2f(v4u.y), vz = h2f(v4u.z), vw = h2f(v4u.w);
      #pragma unroll
      for (int q = 0; q < 4; ++q) {
        float a = Al[(wvx * 4 + q) * 32 + c];
        acc[q].x += vx * a; acc[q].y += vy * a;
        acc[q].z += vz * a; acc[q].w += vw * a;
      }
    }
    #pragma unroll
    for (int q = 0; q < 4; ++q) {
      ushort4 ob;
      ob.x = f2h(acc[q].x); ob.y = f2h(acc[q].y);
      ob.z = f2h(acc[q].z); ob.w = f2h(acc[q].w);
      *reinterpret_cast<ushort4*>(
          oH + (size_t)(tb + wvx * 4 + q) * 1024 + h * 256 + p4) = ob;
    }
  }
}

// ---------------------------------------------------------------- kernel D2
__global__ __launch_bounds__(256) void kD2(u16* __restrict__ wkvG,
                                           const float* __restrict__ decayG) {
  const int wvid = (blockIdx.x * 256 + threadIdx.x) >> 6;  // 0..1023
  const int lane = threadIdx.x & 63;
  const int p4 = lane * 4;
  const int d = wvid & 127;
  const int bh = wvid >> 7;
  u16* base = wkvG + ((size_t)bh * 64 * 128 + d) * 256 + p4;
  const float* dbase = decayG + (size_t)bh * 64 * 128 + d;
  ushort4 kvb[4];
  float decb[4];
  #pragma unroll
  for (int i = 0; i < 4; ++i) {
    kvb[i] = *reinterpret_cast<const ushort4*>(base + (size_t)i * 32768);
    decb[i] = dbase[(size_t)i * 128];
  }
  float4 S = make_float4(0.f, 0.f, 0.f, 0.f);
  #pragma unroll
  for (int nc = 0; nc < 64; ++nc) {
    const int sl = nc & 3;
    ushort4 kv = kvb[sl];
    float dec = decb[sl];
    if (nc + 4 < 64) {
      kvb[sl] = *reinterpret_cast<const ushort4*>(base + (size_t)(nc + 4) * 32768);
      decb[sl] = dbase[(size_t)(nc + 4) * 128];
    }
    ushort4 ob;
    ob.x = f2h(S.x); ob.y = f2h(S.y); ob.z = f2h(S.z); ob.w = f2h(S.w);
    *reinterpret_cast<ushort4*>(base + (size_t)nc * 32768) = ob;
    S.x = S.x * dec + h2f(kv.x);
    S.y = S.y * dec + h2f(kv.y);
    S.z = S.z * dec + h2f(kv.z);
    S.w = S.w * dec + h2f(kv.w);
  }
}

// ---------------------------------------------------------------- kernel D3 (+GN+swish fused)
__global__ __launch_bounds__(256) void kD3(
    const u16* __restrict__ qeH, const u16* __restrict__ wkvG,
    const u16* __restrict__ oH, const u16* __restrict__ gG,
    const float* __restrict__ gn_w, const float* __restrict__ gn_b,
    u16* __restrict__ gate) {
  __shared__ float qel[32 * 129];
  const int tid = threadIdx.x;
  const int bid = blockIdx.x;
  const int nc = bid & 63, h = (bid >> 6) & 3, b = bid >> 8;
  const int tb = b * Lc + nc * 32;
  for (int it = 0; it < 16; ++it) {
    int idx = it * 256 + tid;
    int c = idx >> 7, d = idx & 127;
    qel[c * 129 + d] = h2f(qeH[(size_t)(tb + c) * 512 + h * 128 + d]);
  }
  __syncthreads();
  const int pid = tid & 63, wvx = tid >> 6;
  const int p4 = pid * 4;
  const int vd = h * 256 + p4;
  const float4 gw = ld4(gn_w + vd), gb = ld4(gn_b + vd);
  const u16* Sb = wkvG + (size_t)bid * (128 * 256);
  float4 acc[8];
  #pragma unroll
  for (int q = 0; q < 8; ++q) acc[q] = make_float4(0, 0, 0, 0);
  for (int d = 0; d < 128; ++d) {
    ushort4 s4 = *reinterpret_cast<const ushort4*>(Sb + (size_t)d * 256 + p4);
    float sx = h2f(s4.x), sy = h2f(s4.y), sz = h2f(s4.z), sw = h2f(s4.w);
    #pragma unroll
    for (int q = 0; q < 8; ++q) {
      float qv = qel[(wvx * 8 + q) * 129 + d];
      acc[q].x += sx * qv; acc[q].y += sy * qv;
      acc[q].z += sz * qv; acc[q].w += sw * qv;
    }
  }
  #pragma unroll
  for (int q = 0; q < 8; ++q) {
    const int t = tb + wvx * 8 + q;
    ushort4 c4 = *reinterpret_cast<const ushort4*>(oH + (size_t)t * 1024 + vd);
    float4 o4;
    o4.x = h2f(c4.x) + acc[q].x; o4.y = h2f(c4.y) + acc[q].y;
    o4.z = h2f(c4.z) + acc[q].z; o4.w = h2f(c4.w) + acc[q].w;
    float s = o4.x + o4.y + o4.z + o4.w;
    float ss = o4.x * o4.x + o4.y * o4.y + o4.z * o4.z + o4.w * o4.w;
    #pragma unroll
    for (int m = 1; m < 64; m <<= 1) {
      s += __shfl_xor(s, m, 64);
      ss += __shfl_xor(ss, m, 64);
    }
    const float mean = s * (1.f / 256.f);
    const float var = ss * (1.f / 256.f) - mean * mean;
    const float rs = rsqrtf(var + 1e-5f);
    float4 on;
    on.x = (o4.x - mean) * rs * gw.x + gb.x;
    on.y = (o4.y - mean) * rs * gw.y + gb.y;
    on.z = (o4.z - mean) * rs * gw.z + gb.z;
    on.w = (o4.w - mean) * rs * gw.w + gb.w;
    ushort4 g4 = *reinterpret_cast<const ushort4*>(gG + (size_t)t * 1024 + vd);
    float gx = h2f(g4.x), gy = h2f(g4.y), gz = h2f(g4.z), gw_ = h2f(g4.w);
    float4 sw;
    sw.x = gx / (1.f + __expf(-gx));
    sw.y = gy / (1.f + __expf(-gy));
    sw.z = gz / (1.f + __expf(-gz));
    sw.w = gw_ / (1.f + __expf(-gw_));
    ushort4 ob;
    ob.x = f2h(on.x * sw.x); ob.y = f2h(on.y * sw.y);
    ob.z = f2h(on.z * sw.z); ob.w = f2h(on.w * sw.w);
    *reinterpret_cast<ushort4*>(gate + (size_t)t * 1024 + vd) = ob;
  }
}

// ---------------------------------------------------------------- kernel F (f16)
__global__ __launch_bounds__(256) void kF(
    const u16* __restrict__ gate, const u16* __restrict__ owb,
    float* __restrict__ out) {
  __shared__ __align__(16) u16 Abuf[128 * 64];
  __shared__ __align__(16) u16 Bbuf[128 * 64];
  const int mt = blockIdx.x, nt = blockIdx.y;
  const u16* A = gate + (size_t)mt * 128 * 1024;
  const u16* W = owb + (size_t)nt * 128 * 1024;
  float* C = out + (size_t)mt * 128 * 1024 + nt * 128;
  const int tid = threadIdx.x;
  const int lane = tid & 63;
  const int wv = tid >> 6;
  const int wr = wv >> 1, wc = wv & 1;
  const int srow = wv * 32;
  f32x4 acc[4][4];
  #pragma unroll
  for (int i = 0; i < 4; ++i)
    #pragma unroll
    for (int j = 0; j < 4; ++j) acc[i][j] = {0.f, 0.f, 0.f, 0.f};
  for (int k0 = 0; k0 < 1024; k0 += 64) {
    #pragma unroll
    for (int c = 0; c < 4; ++c) {
      const int s8 = srow + c * 8;
      stage_swz(A, Abuf, s8, k0, lane);
      stage_swz(W, Bbuf, s8, k0, lane);
    }
    __syncthreads();
    #pragma unroll
    for (int kk = 0; kk < 2; ++kk) {
      const int sl = kk * 4 + (lane >> 4);
      f16x8 af[4], bf[4];
      #pragma unroll
      for (int m = 0; m < 4; ++m)
        af[m] = read_swz(Abuf, wr * 64 + m * 16 + (lane & 15), sl);
      #pragma unroll
      for (int j = 0; j < 4; ++j)
        bf[j] = read_swz(Bbuf, wc * 64 + j * 16 + (lane & 15), sl);
      #pragma unroll
      for (int m = 0; m < 4; ++m)
        #pragma unroll
        for (int j = 0; j < 4; ++j)
          acc[m][j] = __builtin_amdgcn_mfma_f32_16x16x32_f16(af[m], bf[j], acc[m][j], 0, 0, 0);
    }
    __syncthreads();
  }
  #pragma unroll
  for (int m = 0; m < 4; ++m)
    #pragma unroll
    for (int r = 0; r < 4; ++r) {
      const int row = wr * 64 + m * 16 + (lane >> 4) * 4 + r;
      #pragma unroll
      for (int j = 0; j < 4; ++j) {
        const int col = wc * 64 + j * 16 + (lane & 15);
        C[(size_t)row * 1024 + col] = acc[m][j][r];
      }
    }
}

}  // namespace

extern "C" void kernel_launch(void* const* d_in, const int* in_sizes, int n_in,
                              void* d_out, int out_size, void* d_ws, size_t ws_size,
                              hipStream_t stream) {
  (void)in_sizes; (void)n_in; (void)out_size;
  if (ws_size < WS_NEED) return;

  const float* x      = (const float*)d_in[0];
  const float* x0_mu  = (const float*)d_in[1];
  const float* x0_w   = (const float*)d_in[2];
  const float* x2_w   = (const float*)d_in[3];
  const float* x_bias = (const float*)d_in[4];
  const float* r_w    = (const float*)d_in[5];
  const float* w_w1   = (const float*)d_in[6];
  const float* w_w2   = (const float*)d_in[7];
  const float* w_b2   = (const float*)d_in[8];
  const float* k_w    = (const float*)d_in[9];
  const float* v_w    = (const float*)d_in[10];
  const float* g_w    = (const float*)d_in[11];
  const float* bonus  = (const float*)d_in[12];
  const float* gn_w   = (const float*)d_in[13];
  const float* gn_b   = (const float*)d_in[14];
  const float* o_w    = (const float*)d_in[15];
  float* out = (float*)d_out;
  char* ws = (char*)d_ws;

  u16*   wkvG   = (u16*)(ws + OFF_WKV);
  u16*   xm0f   = (u16*)(ws + OFF_XM0F);
  u16*   deltaf = (u16*)(ws + OFF_DELTAF);
  float* t160   = (float*)(ws + OFF_T160);
  float* xmw    = (float*)(ws + OFF_XMW);
  u16*   x0wf   = (u16*)(ws + OFF_X0WF);
  float* ywp    = (float*)(ws + OFF_YWP);
  u16*   xmf    = (u16*)(ws + OFF_XMF);
  float* wfin   = (float*)(ws + OFF_WFIN);
  u16*   gate   = (u16*)(ws + OFF_GATE);
  u16*   qeH    = (u16*)(ws + OFF_QE);
  u16*   oH     = (u16*)(ws + OFF_OO);
  u16*   Wf     = (u16*)(ws + OFF_WF);
  float* decayG = (float*)(ws + OFF_DECAY);
  u16*   owb    = (u16*)(ws + OFF_OWB);
  u16*   rG     = (u16*)(ws + OFF_RG);
  u16*   kG     = (u16*)(ws + OFF_KG);
  u16*   vG     = (u16*)(ws + OFF_VG);
  u16*   gG     = (u16*)(ws + OFF_GG);

  kWA  <<<dim3(8352),        dim3(256), 0, stream>>>(r_w, k_w, v_w, g_w, o_w, x0_w,
                                                     x, x0_mu, Wf, owb, x0wf,
                                                     xm0f, deltaf);
  kA2f <<<dim3(32, 2),       dim3(256), 0, stream>>>(xm0f, x0wf, t160);
  kA2m5<<<dim3(5, 64, 16),   dim3(256), 0, stream>>>(t160, x2_w, x_bias, xm0f,
                                                     deltaf, x0_mu, xmf, xmw);
  kWL  <<<dim3(128, 4),      dim3(256), 0, stream>>>(xmw, w_w1, ywp);
  kB   <<<dim3(32, 24),      dim3(256), 0, stream>>>(xmf, Wf, rG, kG, vG, gG);
  kC   <<<dim3(128, 2),      dim3(256), 0, stream>>>(ywp, w_w2, w_b2, wfin);
  kD1  <<<dim3(512),         dim3(512), 0, stream>>>(rG, kG, vG, wfin, bonus,
                                                     wkvG, decayG, qeH, oH);
  kD2  <<<dim3(256),         dim3(256), 0, stream>>>(wkvG, decayG);
  kD3  <<<dim3(512),         dim3(256), 0, stream>>>(qeH, wkvG, oH, gG,
                                                     gn_w, gn_b, gate);
  kF   <<<dim3(32, 8),       dim3(256), 0, stream>>>(gate, owb, out);
}